// Round 3
// baseline (421.385 us; speedup 1.0000x reference)
//
#include <hip/hip_runtime.h>
#include <math.h>

#define NE   1024
#define ED   256
#define NT   131072

typedef __attribute__((ext_vector_type(8))) short short8;
typedef __attribute__((ext_vector_type(4))) float f32x4;

__device__ inline unsigned short f2bf(float f) {
    unsigned u = __float_as_uint(f);
    unsigned r = (u + 0x7FFFu + ((u >> 16) & 1u)) >> 16;   // RNE
    return (unsigned short)r;
}

__device__ inline void gl_lds16(const void* g, void* l) {
    __builtin_amdgcn_global_load_lds(
        (const __attribute__((address_space(1))) unsigned int*)g,
        (__attribute__((address_space(3))) unsigned int*)l, 16, 0, 0);
}

// packed candidate: (q(s~) << 16) | code ; q monotone in s~ so u32-min is
// lexicographic (s~, code)-min. q = floor((s + 1024) * 16), clamped.
__device__ inline unsigned pack_cand(float s, int code) {
    float qf = (s + 1024.f) * 16.f;
    int q = (int)qf;
    q = q < 0 ? 0 : (q > 65535 ? 65535 : q);
    return ((unsigned)q << 16) | (unsigned)code;
}

// ---------------------------------------------------------------------------
// ws layout:
//   0        wnorm  f32[1024]
//   4096     counts int[1024]
//   8192     wmax   f32[1]
//   8448     wb     bf16[1024*256]   (512 KB)
//   532736   cnt    u32[131072]      (512 KB)
//   1057024  cand   u32[131072*32]   (16 MB)
// ---------------------------------------------------------------------------

__global__ __launch_bounds__(256) void vq_prep(const float* __restrict__ w,
                                               float* __restrict__ wnorm,
                                               int* __restrict__ counts,
                                               unsigned short* __restrict__ wb) {
    int c = blockIdx.x * 256 + threadIdx.x;
    if (c < NE) {
        const float4* row = reinterpret_cast<const float4*>(w + (size_t)c * ED);
        ushort4* wbr = reinterpret_cast<ushort4*>(wb + (size_t)c * ED);
        float s = 0.f;
#pragma unroll 8
        for (int i = 0; i < ED / 4; ++i) {
            float4 v = row[i];
            s += v.x * v.x + v.y * v.y + v.z * v.z + v.w * v.w;
            ushort4 o;
            o.x = f2bf(v.x); o.y = f2bf(v.y); o.z = f2bf(v.z); o.w = f2bf(v.w);
            wbr[i] = o;
        }
        wnorm[c] = s;
        counts[c] = 0;
    }
}

__global__ __launch_bounds__(1024) void vq_wmax(const float* __restrict__ wnorm,
                                                float* __restrict__ wmax) {
    __shared__ float red[16];
    int tid = threadIdx.x;
    float v = wnorm[tid];
#pragma unroll
    for (int m = 32; m >= 1; m >>= 1) v = fmaxf(v, __shfl_xor(v, m, 64));
    if ((tid & 63) == 0) red[tid >> 6] = v;
    __syncthreads();
    if (tid == 0) {
        float m = red[0];
#pragma unroll
        for (int i = 1; i < 16; ++i) m = fmaxf(m, red[i]);
        wmax[0] = sqrtf(m);
    }
}

// bf16-MFMA scores, pipelined double-buffered staging, candidate shortlist.
// 512 threads (8 waves x 32 tokens), 16 tiles of 64 codes, 2 x 32KB LDS buffers.
__global__ __launch_bounds__(512, 4) void vq_score(const float* __restrict__ z,
                                                   const unsigned short* __restrict__ wb,
                                                   const float* __restrict__ wnorm,
                                                   const float* __restrict__ wmaxp,
                                                   unsigned* __restrict__ cnt,
                                                   unsigned* __restrict__ cand) {
    __shared__ __align__(16) unsigned short wlds[2][16384]; // 2 x 32 KB
    __shared__ float wn_lds[NE];                            // 4 KB
    __shared__ float thr_lds[8][32];                        // 1 KB

    const int tid  = threadIdx.x;
    const int lane = tid & 63;
    const int wv_  = tid >> 6;          // 0..7
    const int l15  = lane & 15;
    const int l4   = lane >> 4;
    const int row0 = blockIdx.x * 256 + wv_ * 32;

    reinterpret_cast<float2*>(wn_lds)[tid] = reinterpret_cast<const float2*>(wnorm)[tid];
    if (tid < 256) cnt[blockIdx.x * 256 + tid] = 0;

    // ---- A: z fp32 -> bf16 fragments (row=l15, k=kg*32 + l4*8 + i) ----
    short8 a[2][8];
    float zn2[2];
#pragma unroll
    for (int mi = 0; mi < 2; ++mi) {
        const float* zr = z + (size_t)(row0 + mi * 16 + l15) * ED;
        float s = 0.f;
#pragma unroll
        for (int kg = 0; kg < 8; ++kg) {
            int k0 = kg * 32 + l4 * 8;
            float4 p = *reinterpret_cast<const float4*>(zr + k0);
            float4 q = *reinterpret_cast<const float4*>(zr + k0 + 4);
            s += p.x * p.x + p.y * p.y + p.z * p.z + p.w * p.w
               + q.x * q.x + q.y * q.y + q.z * q.z + q.w * q.w;
            short8 t;
            t[0] = (short)f2bf(p.x); t[1] = (short)f2bf(p.y);
            t[2] = (short)f2bf(p.z); t[3] = (short)f2bf(p.w);
            t[4] = (short)f2bf(q.x); t[5] = (short)f2bf(q.y);
            t[6] = (short)f2bf(q.z); t[7] = (short)f2bf(q.w);
            a[mi][kg] = t;
        }
        zn2[mi] = s;
    }
#pragma unroll
    for (int mi = 0; mi < 2; ++mi) {
        zn2[mi] += __shfl_xor(zn2[mi], 16, 64);
        zn2[mi] += __shfl_xor(zn2[mi], 32, 64);
    }
    float wmax = wmaxp[0];
#pragma unroll
    for (int mi = 0; mi < 2; ++mi)
        thr_lds[wv_][mi * 16 + l15] = 0.0313f * sqrtf(zn2[mi]) * wmax + 0.05f;

    // ---- prologue: stage tile 0 into buffer 0 ----
    // fragment s = nj*8+kg (1 KB each); wave wv_ stages s = wv_*4+p
    {
#pragma unroll
        for (int p = 0; p < 4; ++p) {
            int s  = wv_ * 4 + p;
            int nj = s >> 3, kg = s & 7;
            int j  = nj * 16 + l15;                      // c0 = 0
            gl_lds16(wb + (size_t)j * ED + kg * 32 + l4 * 8, &wlds[0][s * 512]);
        }
    }

    float mn[2][4], thrR[2][4];
#pragma unroll
    for (int mi = 0; mi < 2; ++mi)
#pragma unroll
        for (int r = 0; r < 4; ++r) mn[mi][r] = 3.4e38f;

    for (int ct = 0; ct < 16; ++ct) {
        const int c0 = ct * 64;
        const int b  = ct & 1;

        // my stage(ct) loads + my prev ds traffic complete, then rendezvous:
        asm volatile("s_waitcnt vmcnt(0) lgkmcnt(0)" ::: "memory");
        __builtin_amdgcn_s_barrier();
        // now: buf b fully staged by ALL waves; all waves done reading buf b^1
        if (ct < 15) {
            const int c1 = c0 + 64;
#pragma unroll
            for (int p = 0; p < 4; ++p) {
                int s  = wv_ * 4 + p;
                int nj = s >> 3, kg = s & 7;
                int j  = c1 + nj * 16 + l15;
                gl_lds16(wb + (size_t)j * ED + kg * 32 + l4 * 8,
                         &wlds[b ^ 1][s * 512]);
            }
        }
        if (ct == 0) {
#pragma unroll
            for (int mi = 0; mi < 2; ++mi)
#pragma unroll
                for (int r = 0; r < 4; ++r)
                    thrR[mi][r] = thr_lds[wv_][mi * 16 + l4 * 4 + r];
        }

        f32x4 acc[2][4];
#pragma unroll
        for (int mi = 0; mi < 2; ++mi)
#pragma unroll
            for (int nj = 0; nj < 4; ++nj) acc[mi][nj] = {0.f, 0.f, 0.f, 0.f};

#pragma unroll
        for (int kg = 0; kg < 8; ++kg) {
#pragma unroll
            for (int nj = 0; nj < 4; ++nj) {
                short8 wf = *reinterpret_cast<const short8*>(
                    &wlds[b][(nj * 8 + kg) * 512 + lane * 8]);
                acc[0][nj] = __builtin_amdgcn_mfma_f32_16x16x32_bf16(a[0][kg], wf, acc[0][nj], 0, 0, 0);
                acc[1][nj] = __builtin_amdgcn_mfma_f32_16x16x32_bf16(a[1][kg], wf, acc[1][nj], 0, 0, 0);
            }
        }

        float wnv[4];
#pragma unroll
        for (int nj = 0; nj < 4; ++nj) wnv[nj] = wn_lds[c0 + nj * 16 + l15];

        float tmin[2][4];
#pragma unroll
        for (int mi = 0; mi < 2; ++mi)
#pragma unroll
            for (int r = 0; r < 4; ++r) tmin[mi][r] = 3.4e38f;
#pragma unroll
        for (int mi = 0; mi < 2; ++mi)
#pragma unroll
            for (int nj = 0; nj < 4; ++nj)
#pragma unroll
                for (int r = 0; r < 4; ++r) {
                    float s = fmaf(-2.f, acc[mi][nj][r], wnv[nj]);
                    tmin[mi][r] = fminf(tmin[mi][r], s);
                }
#pragma unroll
        for (int m = 1; m < 16; m <<= 1)
#pragma unroll
            for (int mi = 0; mi < 2; ++mi)
#pragma unroll
                for (int r = 0; r < 4; ++r)
                    tmin[mi][r] = fminf(tmin[mi][r], __shfl_xor(tmin[mi][r], m, 64));
#pragma unroll
        for (int mi = 0; mi < 2; ++mi)
#pragma unroll
            for (int r = 0; r < 4; ++r) mn[mi][r] = fminf(mn[mi][r], tmin[mi][r]);

        // append candidates: s <= runmin + thr  (runmin >= final min => superset)
#pragma unroll
        for (int mi = 0; mi < 2; ++mi)
#pragma unroll
            for (int nj = 0; nj < 4; ++nj)
#pragma unroll
                for (int r = 0; r < 4; ++r) {
                    float s = fmaf(-2.f, acc[mi][nj][r], wnv[nj]);
                    if (s <= mn[mi][r] + thrR[mi][r]) {
                        int tok  = row0 + mi * 16 + l4 * 4 + r;
                        int code = c0 + nj * 16 + l15;
                        unsigned pos = atomicAdd(&cnt[tok], 1u);
                        if (pos < 32u) cand[(size_t)tok * 32 + pos] = pack_cand(s, code);
                    }
                }
    }
}

// Exact fp32 refine: wave-parallel prune on packed (q,code), then exact
// evaluation of survivors (identical arithmetic per candidate => picks
// identical to evaluating the full list).
__global__ __launch_bounds__(256) void vq_refine(const float* __restrict__ z,
                                                 const float* __restrict__ w,
                                                 const float* __restrict__ wnorm,
                                                 const float* __restrict__ wmaxp,
                                                 const unsigned* __restrict__ cnt,
                                                 const unsigned* __restrict__ cand,
                                                 int* __restrict__ counts,
                                                 float* __restrict__ out) {
    const int lane = threadIdx.x & 63;
    const int t = blockIdx.x * 4 + (threadIdx.x >> 6);
    float4 zv = reinterpret_cast<const float4*>(z + (size_t)t * ED)[lane];
    unsigned n = cnt[t];
    float bs = 3.4e38f;
    int bj = NE;

    if (n >= 1u && n <= 32u) {
        unsigned pk = 0xFFFFFFFFu;
        if (lane < (int)n) pk = cand[(size_t)t * 32 + lane];
        unsigned pmin = pk;
#pragma unroll
        for (int m = 1; m < 64; m <<= 1) {
            unsigned o = __shfl_xor(pmin, m, 64);
            pmin = o < pmin ? o : pmin;
        }
        // same thr formula as score; margin covers 2 quantization steps
        float zn = zv.x * zv.x + zv.y * zv.y + zv.z * zv.z + zv.w * zv.w;
#pragma unroll
        for (int m = 1; m < 64; m <<= 1) zn += __shfl_xor(zn, m, 64);
        float thr = 0.0313f * sqrtf(zn) * wmaxp[0] + 0.05f;
        unsigned margin = (unsigned)(16.f * thr) + 2u;
        unsigned qmin = pmin >> 16;
        bool keep = (lane < (int)n) && ((pk >> 16) <= qmin + margin);
        unsigned long long mask = __ballot(keep);
        while (mask) {
            int c = __ffsll(mask) - 1;
            mask &= mask - 1;
            int j = (int)(__shfl(pk, c, 64) & 0xFFFFu);
            float4 wv = reinterpret_cast<const float4*>(w + (size_t)j * ED)[lane];
            float d = fmaf(zv.x, wv.x, fmaf(zv.y, wv.y, fmaf(zv.z, wv.z, zv.w * wv.w)));
#pragma unroll
            for (int m = 1; m < 64; m <<= 1) d += __shfl_xor(d, m, 64);
            float s = fmaf(-2.f, d, wnorm[j]);
            if (s < bs || (s == bs && j < bj)) { bs = s; bj = j; }
        }
    } else {
        // overflow (or impossible empty): exact scan of all codes
        for (int j = 0; j < NE; ++j) {
            float4 wv = reinterpret_cast<const float4*>(w + (size_t)j * ED)[lane];
            float d = fmaf(zv.x, wv.x, fmaf(zv.y, wv.y, fmaf(zv.z, wv.z, zv.w * wv.w)));
#pragma unroll
            for (int m = 1; m < 64; m <<= 1) d += __shfl_xor(d, m, 64);
            float s = fmaf(-2.f, d, wnorm[j]);
            if (s < bs || (s == bs && j < bj)) { bs = s; bj = j; }
        }
    }
    float4 bw = reinterpret_cast<const float4*>(w + (size_t)bj * ED)[lane];
    reinterpret_cast<float4*>(out + (size_t)t * ED)[lane] = bw;
    if (lane == 0) atomicAdd(&counts[bj], 1);
}

__global__ __launch_bounds__(1024) void vq_pplx(const int* __restrict__ counts,
                                                float* __restrict__ out) {
    __shared__ float red[16];
    int tid = threadIdx.x;
    float e = (float)counts[tid] * (1.0f / (float)NT);
    float t = -e * logf(e + 1e-10f);
#pragma unroll
    for (int m = 32; m >= 1; m >>= 1) t += __shfl_down(t, m, 64);
    if ((tid & 63) == 0) red[tid >> 6] = t;
    __syncthreads();
    if (tid < 16) {
        float s = red[tid];
#pragma unroll
        for (int m = 8; m >= 1; m >>= 1) s += __shfl_down(s, m, 16);
        if (tid == 0) out[(size_t)NT * ED] = expf(s);
    }
}

// ======================= fallback (round-1, fp32 VALU) =======================
#define TM 64
#define TN 64
#define KC 64

__global__ __launch_bounds__(256) void vq_prep0(const float* __restrict__ w,
                                                float* __restrict__ wnorm,
                                                int* __restrict__ counts) {
    int c = blockIdx.x * blockDim.x + threadIdx.x;
    if (c < NE) {
        const float4* row = reinterpret_cast<const float4*>(w + (size_t)c * ED);
        float s = 0.f;
#pragma unroll 8
        for (int i = 0; i < ED / 4; ++i) {
            float4 v = row[i];
            s += v.x * v.x + v.y * v.y + v.z * v.z + v.w * v.w;
        }
        wnorm[c] = s;
        counts[c] = 0;
    }
}

__global__ __launch_bounds__(256) void vq_argmin0(const float* __restrict__ z,
                                                  const float* __restrict__ w,
                                                  const float* __restrict__ wnorm,
                                                  int* __restrict__ idx_out,
                                                  int* __restrict__ counts) {
    __shared__ float zs[ED][TM];
    __shared__ float wsh[KC][TN];
    const int tid  = threadIdx.x;
    const int row0 = blockIdx.x * TM;
    const int cg   = tid & 15;
    const int tg   = tid >> 4;
#pragma unroll
    for (int p = 0; p < 16; ++p) {
        int f = p * 256 + tid;
        int k = f >> 4;
        int g = f & 15;
        float4 v;
        v.x = z[(size_t)(row0 + g * 4 + 0) * ED + k];
        v.y = z[(size_t)(row0 + g * 4 + 1) * ED + k];
        v.z = z[(size_t)(row0 + g * 4 + 2) * ED + k];
        v.w = z[(size_t)(row0 + g * 4 + 3) * ED + k];
        *reinterpret_cast<float4*>(&zs[k][g * 4]) = v;
    }
    float best[4];
    int   bidx[4];
#pragma unroll
    for (int i = 0; i < 4; ++i) { best[i] = 3.4e38f; bidx[i] = 0; }
    for (int ct = 0; ct < NE / TN; ++ct) {
        const int c0 = ct * TN;
        float acc[4][4];
#pragma unroll
        for (int i = 0; i < 4; ++i)
#pragma unroll
            for (int j = 0; j < 4; ++j) acc[i][j] = 0.f;
        for (int kc = 0; kc < ED / KC; ++kc) {
            __syncthreads();
#pragma unroll
            for (int p = 0; p < 4; ++p) {
                int f = p * 256 + tid;
                int k = f >> 4;
                int g = f & 15;
                float4 v;
                v.x = w[(size_t)(c0 + g * 4 + 0) * ED + kc * KC + k];
                v.y = w[(size_t)(c0 + g * 4 + 1) * ED + kc * KC + k];
                v.z = w[(size_t)(c0 + g * 4 + 2) * ED + kc * KC + k];
                v.w = w[(size_t)(c0 + g * 4 + 3) * ED + kc * KC + k];
                *reinterpret_cast<float4*>(&wsh[k][g * 4]) = v;
            }
            __syncthreads();
#pragma unroll 8
            for (int k = 0; k < KC; ++k) {
                float4 zv = *reinterpret_cast<const float4*>(&zs[kc * KC + k][tg * 4]);
                float4 wv = *reinterpret_cast<const float4*>(&wsh[k][cg * 4]);
                float zr[4] = { zv.x, zv.y, zv.z, zv.w };
                float wr[4] = { wv.x, wv.y, wv.z, wv.w };
#pragma unroll
                for (int i = 0; i < 4; ++i)
#pragma unroll
                    for (int j = 0; j < 4; ++j)
                        acc[i][j] = fmaf(zr[i], wr[j], acc[i][j]);
            }
        }
#pragma unroll
        for (int j = 0; j < 4; ++j) {
            int c = c0 + cg * 4 + j;
            float wn = wnorm[c];
#pragma unroll
            for (int i = 0; i < 4; ++i) {
                float s = fmaf(-2.f, acc[i][j], wn);
                if (s < best[i]) { best[i] = s; bidx[i] = c; }
            }
        }
    }
#pragma unroll
    for (int m = 1; m < 16; m <<= 1) {
#pragma unroll
        for (int i = 0; i < 4; ++i) {
            float ov = __shfl_xor(best[i], m, 64);
            int   oi = __shfl_xor(bidx[i], m, 64);
            if (ov < best[i] || (ov == best[i] && oi < bidx[i])) {
                best[i] = ov; bidx[i] = oi;
            }
        }
    }
    if (cg == 0) {
#pragma unroll
        for (int i = 0; i < 4; ++i) {
            int t = row0 + tg * 4 + i;
            idx_out[t] = bidx[i];
            atomicAdd(&counts[bidx[i]], 1);
        }
    }
}

__global__ __launch_bounds__(256) void vq_gather0(const float* __restrict__ w,
                                                  const int* __restrict__ idx,
                                                  float* __restrict__ out) {
    int tid = threadIdx.x;
    int t   = blockIdx.x * 4 + (tid >> 6);
    int c4  = tid & 63;
    int id  = idx[t];
    float4 v = reinterpret_cast<const float4*>(w + (size_t)id * ED)[c4];
    reinterpret_cast<float4*>(out + (size_t)t * ED)[c4] = v;
}
// ============================================================================

extern "C" void kernel_launch(void* const* d_in, const int* in_sizes, int n_in,
                              void* d_out, int out_size, void* d_ws, size_t ws_size,
                              hipStream_t stream) {
    const float* z = (const float*)d_in[0];
    const float* w = (const float*)d_in[1];
    float* out = (float*)d_out;
    char* ws = (char*)d_ws;

    float*          wnorm  = (float*)ws;
    int*            counts = (int*)(ws + 4096);
    float*          wmax   = (float*)(ws + 8192);
    unsigned short* wb     = (unsigned short*)(ws + 8448);
    unsigned*       cnt    = (unsigned*)(ws + 532736);
    unsigned*       cand   = (unsigned*)(ws + 1057024);
    const size_t need = 1057024 + (size_t)NT * 32 * 4;

    if (ws_size >= need) {
        vq_prep<<<4, 256, 0, stream>>>(w, wnorm, counts, wb);
        vq_wmax<<<1, 1024, 0, stream>>>(wnorm, wmax);
        vq_score<<<NT / 256, 512, 0, stream>>>(z, wb, wnorm, wmax, cnt, cand);
        vq_refine<<<NT / 4, 256, 0, stream>>>(z, w, wnorm, wmax, cnt, cand, counts, out);
        vq_pplx<<<1, 1024, 0, stream>>>(counts, out);
    } else {
        int* idxw = (int*)(ws + 8192);
        vq_prep0<<<(NE + 255) / 256, 256, 0, stream>>>(w, wnorm, counts);
        vq_argmin0<<<NT / TM, 256, 0, stream>>>(z, w, wnorm, idxw, counts);
        vq_gather0<<<NT / 4, 256, 0, stream>>>(w, idxw, out);
        vq_pplx<<<1, 1024, 0, stream>>>(counts, out);
    }
}

// Round 4
// 395.066 us; speedup vs baseline: 1.0666x; 1.0666x over previous
//
#include <hip/hip_runtime.h>
#include <math.h>

#define NE   1024
#define ED   256
#define NT   131072

typedef __attribute__((ext_vector_type(8))) short short8;
typedef __attribute__((ext_vector_type(4))) float f32x4;

__device__ inline unsigned short f2bf(float f) {
    unsigned u = __float_as_uint(f);
    unsigned r = (u + 0x7FFFu + ((u >> 16) & 1u)) >> 16;   // RNE
    return (unsigned short)r;
}

__device__ inline void gl_lds16(const void* g, void* l) {
    __builtin_amdgcn_global_load_lds(
        (const __attribute__((address_space(1))) unsigned int*)g,
        (__attribute__((address_space(3))) unsigned int*)l, 16, 0, 0);
}

// packed candidate: (q(s~) << 16) | code ; q monotone in s~ so u32-min is
// lexicographic (s~, code)-min. q = floor((s + 1024) * 16), clamped.
__device__ inline unsigned pack_cand(float s, int code) {
    float qf = (s + 1024.f) * 16.f;
    int q = (int)qf;
    q = q < 0 ? 0 : (q > 65535 ? 65535 : q);
    return ((unsigned)q << 16) | (unsigned)code;
}

// ---------------------------------------------------------------------------
// ws layout:
//   0        wnorm  f32[1024]
//   4096     counts int[1024]
//   8192     wmax   f32[1]
//   8448     wb     bf16[1024*256]   (512 KB)
//   532736   cnt    u32[131072]      (512 KB)
//   1057024  cand   u32[131072*32]   (16 MB)
// ---------------------------------------------------------------------------

__global__ __launch_bounds__(256) void vq_prep(const float* __restrict__ w,
                                               float* __restrict__ wnorm,
                                               int* __restrict__ counts,
                                               unsigned short* __restrict__ wb) {
    int c = blockIdx.x * 256 + threadIdx.x;
    if (c < NE) {
        const float4* row = reinterpret_cast<const float4*>(w + (size_t)c * ED);
        ushort4* wbr = reinterpret_cast<ushort4*>(wb + (size_t)c * ED);
        float s = 0.f;
#pragma unroll 8
        for (int i = 0; i < ED / 4; ++i) {
            float4 v = row[i];
            s += v.x * v.x + v.y * v.y + v.z * v.z + v.w * v.w;
            ushort4 o;
            o.x = f2bf(v.x); o.y = f2bf(v.y); o.z = f2bf(v.z); o.w = f2bf(v.w);
            wbr[i] = o;
        }
        wnorm[c] = s;
        counts[c] = 0;
    }
}

__global__ __launch_bounds__(1024) void vq_wmax(const float* __restrict__ wnorm,
                                                float* __restrict__ wmax) {
    __shared__ float red[16];
    int tid = threadIdx.x;
    float v = wnorm[tid];
#pragma unroll
    for (int m = 32; m >= 1; m >>= 1) v = fmaxf(v, __shfl_xor(v, m, 64));
    if ((tid & 63) == 0) red[tid >> 6] = v;
    __syncthreads();
    if (tid == 0) {
        float m = red[0];
#pragma unroll
        for (int i = 1; i < 16; ++i) m = fmaxf(m, red[i]);
        wmax[0] = sqrtf(m);
    }
}

// bf16-MFMA scores, double-buffered pipelined staging, candidate shortlist.
// 256 threads (4 waves x 32 tokens = 128 tokens/block), 16 tiles of 64 codes,
// 2 x 32KB LDS buffers. Round-2 resource shape (no spill) + round-3 pipeline.
__global__ __launch_bounds__(256, 2) void vq_score(const float* __restrict__ z,
                                                   const unsigned short* __restrict__ wb,
                                                   const float* __restrict__ wnorm,
                                                   const float* __restrict__ wmaxp,
                                                   unsigned* __restrict__ cnt,
                                                   unsigned* __restrict__ cand) {
    __shared__ __align__(16) unsigned short wlds[2][16384]; // 2 x 32 KB
    __shared__ float wn_lds[NE];                            // 4 KB
    __shared__ float thr_lds[4][32];                        // 0.5 KB

    const int tid  = threadIdx.x;
    const int lane = tid & 63;
    const int wv_  = tid >> 6;          // 0..3
    const int l15  = lane & 15;
    const int l4   = lane >> 4;
    const int row0 = blockIdx.x * 128 + wv_ * 32;

    reinterpret_cast<float4*>(wn_lds)[tid] = reinterpret_cast<const float4*>(wnorm)[tid];
    if (tid < 128) cnt[blockIdx.x * 128 + tid] = 0;

    // ---- A: z fp32 -> bf16 fragments (row=l15, k=kg*32 + l4*8 + i) ----
    short8 a[2][8];
    float zn2[2];
#pragma unroll
    for (int mi = 0; mi < 2; ++mi) {
        const float* zr = z + (size_t)(row0 + mi * 16 + l15) * ED;
        float s = 0.f;
#pragma unroll
        for (int kg = 0; kg < 8; ++kg) {
            int k0 = kg * 32 + l4 * 8;
            float4 p = *reinterpret_cast<const float4*>(zr + k0);
            float4 q = *reinterpret_cast<const float4*>(zr + k0 + 4);
            s += p.x * p.x + p.y * p.y + p.z * p.z + p.w * p.w
               + q.x * q.x + q.y * q.y + q.z * q.z + q.w * q.w;
            short8 t;
            t[0] = (short)f2bf(p.x); t[1] = (short)f2bf(p.y);
            t[2] = (short)f2bf(p.z); t[3] = (short)f2bf(p.w);
            t[4] = (short)f2bf(q.x); t[5] = (short)f2bf(q.y);
            t[6] = (short)f2bf(q.z); t[7] = (short)f2bf(q.w);
            a[mi][kg] = t;
        }
        zn2[mi] = s;
    }
#pragma unroll
    for (int mi = 0; mi < 2; ++mi) {
        zn2[mi] += __shfl_xor(zn2[mi], 16, 64);
        zn2[mi] += __shfl_xor(zn2[mi], 32, 64);
    }
    float wmax = wmaxp[0];
#pragma unroll
    for (int mi = 0; mi < 2; ++mi)
        thr_lds[wv_][mi * 16 + l15] = 0.0313f * sqrtf(zn2[mi]) * wmax + 0.05f;

    // ---- prologue: stage tile 0 into buffer 0 ----
    // fragment s = nj*8+kg (1 KB each), 32 frags; wave wv_ stages s = wv_*8+p
#pragma unroll
    for (int p = 0; p < 8; ++p) {
        int s  = wv_ * 8 + p;
        int nj = s >> 3, kg = s & 7;
        int j  = nj * 16 + l15;                      // c0 = 0
        gl_lds16(wb + (size_t)j * ED + kg * 32 + l4 * 8, &wlds[0][s * 512]);
    }

    float mn[2][4], thrR[2][4];
#pragma unroll
    for (int mi = 0; mi < 2; ++mi)
#pragma unroll
        for (int r = 0; r < 4; ++r) mn[mi][r] = 3.4e38f;

    for (int ct = 0; ct < 16; ++ct) {
        const int c0 = ct * 64;
        const int b  = ct & 1;

        // my stage(ct) loads + my prev ds traffic complete, then rendezvous:
        asm volatile("s_waitcnt vmcnt(0) lgkmcnt(0)" ::: "memory");
        __builtin_amdgcn_s_barrier();
        // buf b fully staged by ALL waves; all waves done reading buf b^1
        if (ct < 15) {
            const int c1 = c0 + 64;
#pragma unroll
            for (int p = 0; p < 8; ++p) {
                int s  = wv_ * 8 + p;
                int nj = s >> 3, kg = s & 7;
                int j  = c1 + nj * 16 + l15;
                gl_lds16(wb + (size_t)j * ED + kg * 32 + l4 * 8,
                         &wlds[b ^ 1][s * 512]);
            }
        }
        if (ct == 0) {
#pragma unroll
            for (int mi = 0; mi < 2; ++mi)
#pragma unroll
                for (int r = 0; r < 4; ++r)
                    thrR[mi][r] = thr_lds[wv_][mi * 16 + l4 * 4 + r];
        }

        f32x4 acc[2][4];
#pragma unroll
        for (int mi = 0; mi < 2; ++mi)
#pragma unroll
            for (int nj = 0; nj < 4; ++nj) acc[mi][nj] = {0.f, 0.f, 0.f, 0.f};

#pragma unroll
        for (int kg = 0; kg < 8; ++kg) {
#pragma unroll
            for (int nj = 0; nj < 4; ++nj) {
                short8 wf = *reinterpret_cast<const short8*>(
                    &wlds[b][(nj * 8 + kg) * 512 + lane * 8]);
                acc[0][nj] = __builtin_amdgcn_mfma_f32_16x16x32_bf16(a[0][kg], wf, acc[0][nj], 0, 0, 0);
                acc[1][nj] = __builtin_amdgcn_mfma_f32_16x16x32_bf16(a[1][kg], wf, acc[1][nj], 0, 0, 0);
            }
        }

        float wnv[4];
#pragma unroll
        for (int nj = 0; nj < 4; ++nj) wnv[nj] = wn_lds[c0 + nj * 16 + l15];

        // pass 1: scores into acc (s = wn - 2*dot), per-thread min
        float tmin[2][4];
#pragma unroll
        for (int mi = 0; mi < 2; ++mi)
#pragma unroll
            for (int r = 0; r < 4; ++r) tmin[mi][r] = 3.4e38f;
#pragma unroll
        for (int mi = 0; mi < 2; ++mi)
#pragma unroll
            for (int nj = 0; nj < 4; ++nj)
#pragma unroll
                for (int r = 0; r < 4; ++r) {
                    float s = fmaf(-2.f, acc[mi][nj][r], wnv[nj]);
                    acc[mi][nj][r] = s;
                    tmin[mi][r] = fminf(tmin[mi][r], s);
                }
        // reduce across the 16 same-l4 lanes (codes), update running min
#pragma unroll
        for (int m = 1; m < 16; m <<= 1)
#pragma unroll
            for (int mi = 0; mi < 2; ++mi)
#pragma unroll
                for (int r = 0; r < 4; ++r)
                    tmin[mi][r] = fminf(tmin[mi][r], __shfl_xor(tmin[mi][r], m, 64));
#pragma unroll
        for (int mi = 0; mi < 2; ++mi)
#pragma unroll
            for (int r = 0; r < 4; ++r) mn[mi][r] = fminf(mn[mi][r], tmin[mi][r]);

        // pass 2: append candidates: s <= runmin + thr (superset of final picks)
#pragma unroll
        for (int mi = 0; mi < 2; ++mi)
#pragma unroll
            for (int nj = 0; nj < 4; ++nj)
#pragma unroll
                for (int r = 0; r < 4; ++r) {
                    float s = acc[mi][nj][r];
                    if (s <= mn[mi][r] + thrR[mi][r]) {
                        int tok  = row0 + mi * 16 + l4 * 4 + r;
                        int code = c0 + nj * 16 + l15;
                        unsigned pos = atomicAdd(&cnt[tok], 1u);
                        if (pos < 32u) cand[(size_t)tok * 32 + pos] = pack_cand(s, code);
                    }
                }
    }
}

// Exact fp32 refine: wave-parallel prune on packed (q,code), then exact
// evaluation of survivors; fused gather of z_q and counts histogram.
__global__ __launch_bounds__(256) void vq_refine(const float* __restrict__ z,
                                                 const float* __restrict__ w,
                                                 const float* __restrict__ wnorm,
                                                 const float* __restrict__ wmaxp,
                                                 const unsigned* __restrict__ cnt,
                                                 const unsigned* __restrict__ cand,
                                                 int* __restrict__ counts,
                                                 float* __restrict__ out) {
    const int lane = threadIdx.x & 63;
    const int t = blockIdx.x * 4 + (threadIdx.x >> 6);
    float4 zv = reinterpret_cast<const float4*>(z + (size_t)t * ED)[lane];
    unsigned n = cnt[t];
    float bs = 3.4e38f;
    int bj = NE;

    if (n >= 1u && n <= 32u) {
        unsigned pk = 0xFFFFFFFFu;
        if (lane < (int)n) pk = cand[(size_t)t * 32 + lane];
        unsigned pmin = pk;
#pragma unroll
        for (int m = 1; m < 64; m <<= 1) {
            unsigned o = __shfl_xor(pmin, m, 64);
            pmin = o < pmin ? o : pmin;
        }
        // same thr formula as score; margin covers 2 quantization steps
        float zn = zv.x * zv.x + zv.y * zv.y + zv.z * zv.z + zv.w * zv.w;
#pragma unroll
        for (int m = 1; m < 64; m <<= 1) zn += __shfl_xor(zn, m, 64);
        float thr = 0.0313f * sqrtf(zn) * wmaxp[0] + 0.05f;
        unsigned margin = (unsigned)(16.f * thr) + 2u;
        unsigned qmin = pmin >> 16;
        bool keep = (lane < (int)n) && ((pk >> 16) <= qmin + margin);
        unsigned long long mask = __ballot(keep);
        while (mask) {
            int c = __ffsll(mask) - 1;
            mask &= mask - 1;
            int j = (int)(__shfl(pk, c, 64) & 0xFFFFu);
            float4 wv = reinterpret_cast<const float4*>(w + (size_t)j * ED)[lane];
            float d = fmaf(zv.x, wv.x, fmaf(zv.y, wv.y, fmaf(zv.z, wv.z, zv.w * wv.w)));
#pragma unroll
            for (int m = 1; m < 64; m <<= 1) d += __shfl_xor(d, m, 64);
            float s = fmaf(-2.f, d, wnorm[j]);
            if (s < bs || (s == bs && j < bj)) { bs = s; bj = j; }
        }
    } else {
        // overflow (or impossible empty): exact scan of all codes
        for (int j = 0; j < NE; ++j) {
            float4 wv = reinterpret_cast<const float4*>(w + (size_t)j * ED)[lane];
            float d = fmaf(zv.x, wv.x, fmaf(zv.y, wv.y, fmaf(zv.z, wv.z, zv.w * wv.w)));
#pragma unroll
            for (int m = 1; m < 64; m <<= 1) d += __shfl_xor(d, m, 64);
            float s = fmaf(-2.f, d, wnorm[j]);
            if (s < bs || (s == bs && j < bj)) { bs = s; bj = j; }
        }
    }
    float4 bw = reinterpret_cast<const float4*>(w + (size_t)bj * ED)[lane];
    reinterpret_cast<float4*>(out + (size_t)t * ED)[lane] = bw;
    if (lane == 0) atomicAdd(&counts[bj], 1);
}

__global__ __launch_bounds__(1024) void vq_pplx(const int* __restrict__ counts,
                                                float* __restrict__ out) {
    __shared__ float red[16];
    int tid = threadIdx.x;
    float e = (float)counts[tid] * (1.0f / (float)NT);
    float t = -e * logf(e + 1e-10f);
#pragma unroll
    for (int m = 32; m >= 1; m >>= 1) t += __shfl_down(t, m, 64);
    if ((tid & 63) == 0) red[tid >> 6] = t;
    __syncthreads();
    if (tid < 16) {
        float s = red[tid];
#pragma unroll
        for (int m = 8; m >= 1; m >>= 1) s += __shfl_down(s, m, 16);
        if (tid == 0) out[(size_t)NT * ED] = expf(s);
    }
}

// ======================= fallback (round-1, fp32 VALU) =======================
#define TM 64
#define TN 64
#define KC 64

__global__ __launch_bounds__(256) void vq_prep0(const float* __restrict__ w,
                                                float* __restrict__ wnorm,
                                                int* __restrict__ counts) {
    int c = blockIdx.x * blockDim.x + threadIdx.x;
    if (c < NE) {
        const float4* row = reinterpret_cast<const float4*>(w + (size_t)c * ED);
        float s = 0.f;
#pragma unroll 8
        for (int i = 0; i < ED / 4; ++i) {
            float4 v = row[i];
            s += v.x * v.x + v.y * v.y + v.z * v.z + v.w * v.w;
        }
        wnorm[c] = s;
        counts[c] = 0;
    }
}

__global__ __launch_bounds__(256) void vq_argmin0(const float* __restrict__ z,
                                                  const float* __restrict__ w,
                                                  const float* __restrict__ wnorm,
                                                  int* __restrict__ idx_out,
                                                  int* __restrict__ counts) {
    __shared__ float zs[ED][TM];
    __shared__ float wsh[KC][TN];
    const int tid  = threadIdx.x;
    const int row0 = blockIdx.x * TM;
    const int cg   = tid & 15;
    const int tg   = tid >> 4;
#pragma unroll
    for (int p = 0; p < 16; ++p) {
        int f = p * 256 + tid;
        int k = f >> 4;
        int g = f & 15;
        float4 v;
        v.x = z[(size_t)(row0 + g * 4 + 0) * ED + k];
        v.y = z[(size_t)(row0 + g * 4 + 1) * ED + k];
        v.z = z[(size_t)(row0 + g * 4 + 2) * ED + k];
        v.w = z[(size_t)(row0 + g * 4 + 3) * ED + k];
        *reinterpret_cast<float4*>(&zs[k][g * 4]) = v;
    }
    float best[4];
    int   bidx[4];
#pragma unroll
    for (int i = 0; i < 4; ++i) { best[i] = 3.4e38f; bidx[i] = 0; }
    for (int ct = 0; ct < NE / TN; ++ct) {
        const int c0 = ct * TN;
        float acc[4][4];
#pragma unroll
        for (int i = 0; i < 4; ++i)
#pragma unroll
            for (int j = 0; j < 4; ++j) acc[i][j] = 0.f;
        for (int kc = 0; kc < ED / KC; ++kc) {
            __syncthreads();
#pragma unroll
            for (int p = 0; p < 4; ++p) {
                int f = p * 256 + tid;
                int k = f >> 4;
                int g = f & 15;
                float4 v;
                v.x = w[(size_t)(c0 + g * 4 + 0) * ED + kc * KC + k];
                v.y = w[(size_t)(c0 + g * 4 + 1) * ED + kc * KC + k];
                v.z = w[(size_t)(c0 + g * 4 + 2) * ED + kc * KC + k];
                v.w = w[(size_t)(c0 + g * 4 + 3) * ED + kc * KC + k];
                *reinterpret_cast<float4*>(&wsh[k][g * 4]) = v;
            }
            __syncthreads();
#pragma unroll 8
            for (int k = 0; k < KC; ++k) {
                float4 zv = *reinterpret_cast<const float4*>(&zs[kc * KC + k][tg * 4]);
                float4 wv = *reinterpret_cast<const float4*>(&wsh[k][cg * 4]);
                float zr[4] = { zv.x, zv.y, zv.z, zv.w };
                float wr[4] = { wv.x, wv.y, wv.z, wv.w };
#pragma unroll
                for (int i = 0; i < 4; ++i)
#pragma unroll
                    for (int j = 0; j < 4; ++j)
                        acc[i][j] = fmaf(zr[i], wr[j], acc[i][j]);
            }
        }
#pragma unroll
        for (int j = 0; j < 4; ++j) {
            int c = c0 + cg * 4 + j;
            float wn = wnorm[c];
#pragma unroll
            for (int i = 0; i < 4; ++i) {
                float s = fmaf(-2.f, acc[i][j], wn);
                if (s < best[i]) { best[i] = s; bidx[i] = c; }
            }
        }
    }
#pragma unroll
    for (int m = 1; m < 16; m <<= 1) {
#pragma unroll
        for (int i = 0; i < 4; ++i) {
            float ov = __shfl_xor(best[i], m, 64);
            int   oi = __shfl_xor(bidx[i], m, 64);
            if (ov < best[i] || (ov == best[i] && oi < bidx[i])) {
                best[i] = ov; bidx[i] = oi;
            }
        }
    }
    if (cg == 0) {
#pragma unroll
        for (int i = 0; i < 4; ++i) {
            int t = row0 + tg * 4 + i;
            idx_out[t] = bidx[i];
            atomicAdd(&counts[bidx[i]], 1);
        }
    }
}

__global__ __launch_bounds__(256) void vq_gather0(const float* __restrict__ w,
                                                  const int* __restrict__ idx,
                                                  float* __restrict__ out) {
    int tid = threadIdx.x;
    int t   = blockIdx.x * 4 + (tid >> 6);
    int c4  = tid & 63;
    int id  = idx[t];
    float4 v = reinterpret_cast<const float4*>(w + (size_t)id * ED)[c4];
    reinterpret_cast<float4*>(out + (size_t)t * ED)[c4] = v;
}
// ============================================================================

extern "C" void kernel_launch(void* const* d_in, const int* in_sizes, int n_in,
                              void* d_out, int out_size, void* d_ws, size_t ws_size,
                              hipStream_t stream) {
    const float* z = (const float*)d_in[0];
    const float* w = (const float*)d_in[1];
    float* out = (float*)d_out;
    char* ws = (char*)d_ws;

    float*          wnorm  = (float*)ws;
    int*            counts = (int*)(ws + 4096);
    float*          wmax   = (float*)(ws + 8192);
    unsigned short* wb     = (unsigned short*)(ws + 8448);
    unsigned*       cnt    = (unsigned*)(ws + 532736);
    unsigned*       cand   = (unsigned*)(ws + 1057024);
    const size_t need = 1057024 + (size_t)NT * 32 * 4;

    if (ws_size >= need) {
        vq_prep<<<4, 256, 0, stream>>>(w, wnorm, counts, wb);
        vq_wmax<<<1, 1024, 0, stream>>>(wnorm, wmax);
        vq_score<<<NT / 128, 256, 0, stream>>>(z, wb, wnorm, wmax, cnt, cand);
        vq_refine<<<NT / 4, 256, 0, stream>>>(z, w, wnorm, wmax, cnt, cand, counts, out);
        vq_pplx<<<1, 1024, 0, stream>>>(counts, out);
    } else {
        int* idxw = (int*)(ws + 8192);
        vq_prep0<<<(NE + 255) / 256, 256, 0, stream>>>(w, wnorm, counts);
        vq_argmin0<<<NT / TM, 256, 0, stream>>>(z, w, wnorm, idxw, counts);
        vq_gather0<<<NT / 4, 256, 0, stream>>>(w, idxw, out);
        vq_pplx<<<1, 1024, 0, stream>>>(counts, out);
    }
}